// Round 1
// baseline (518.609 us; speedup 1.0000x reference)
//
#include <hip/hip_runtime.h>
#include <hip/hip_bf16.h>

// GCN layer: N=100000 nodes, E=1600000 edges, IN=256, OUT=32, fp32.
// Pipeline:
//   1) degree_kernel: deg_out[src]++, deg_in[dst]++ (float atomics)
//   2) gemm_kernel:   h = (feat * out_deg^-0.5) @ W   [N,32] into ws
//   3) aggregate_kernel: out[dst] += h[src]  (32 lanes/edge, f32 atomics)
//   4) finalize_kernel:  out = relu(out * in_deg^-0.5 + bias)

#define IN_F 256
#define OUT_F 32
#define ROWS 64        // rows per block in gemm
#define KT 64          // k-tile in gemm
#define KT_PAD (KT + 4)

__global__ __launch_bounds__(256) void degree_kernel(
    const int* __restrict__ src, const int* __restrict__ dst,
    float* __restrict__ deg_out, float* __restrict__ deg_in, int E) {
  int i = blockIdx.x * 256 + threadIdx.x;
  if (i < E) {
    unsafeAtomicAdd(deg_out + src[i], 1.0f);
    unsafeAtomicAdd(deg_in + dst[i], 1.0f);
  }
}

// h[n][o] = sum_k feat[n][k] * scale_out[n] * W[k][o]
__global__ __launch_bounds__(256, 3) void gemm_kernel(
    const float* __restrict__ feat, const float* __restrict__ W,
    const float* __restrict__ deg_out, float* __restrict__ h, int N) {
  __shared__ float sW[IN_F * OUT_F];     // [k][o], 32 KB
  __shared__ float sF[ROWS * KT_PAD];    // [r][k] padded, ~17 KB

  int tid = threadIdx.x;

  // Load full W (256x32 = 2048 float4) once.
  {
    const float4* W4 = (const float4*)W;
    float4* sW4 = (float4*)sW;
#pragma unroll
    for (int i = 0; i < 8; ++i) sW4[tid + i * 256] = W4[tid + i * 256];
  }

  int row0 = blockIdx.x * ROWS;
  int rg = tid >> 3;          // 0..31 -> rows rg and rg+32
  int cg = (tid & 7) * 4;     // col group start
  float4 acc0 = {0.f, 0.f, 0.f, 0.f};
  float4 acc1 = {0.f, 0.f, 0.f, 0.f};

  for (int kt = 0; kt < IN_F; kt += KT) {
    __syncthreads();  // protect sF from readers of previous tile (and order W load)
    // Stage feat tile: ROWS x KT = 4096 floats = 1024 float4; 4 per thread.
#pragma unroll
    for (int i = 0; i < 4; ++i) {
      int idx = tid + i * 256;       // float4 index 0..1023
      int r = idx >> 4;              // 16 float4 per row
      int kk = (idx & 15) * 4;
      int gr = row0 + r;
      float4 v = {0.f, 0.f, 0.f, 0.f};
      if (gr < N) {
        float dg = deg_out[gr];
        float s = dg < 1.f ? 1.f : rsqrtf(dg);
        v = *(const float4*)(feat + (size_t)gr * IN_F + kt + kk);
        v.x *= s; v.y *= s; v.z *= s; v.w *= s;
      }
      *(float4*)(sF + r * KT_PAD + kk) = v;
    }
    __syncthreads();

    const float* fr0 = sF + rg * KT_PAD;
    const float* fr1 = sF + (rg + 32) * KT_PAD;
#pragma unroll
    for (int k4 = 0; k4 < KT; k4 += 4) {
      float4 a0 = *(const float4*)(fr0 + k4);
      float4 a1 = *(const float4*)(fr1 + k4);
#pragma unroll
      for (int j = 0; j < 4; ++j) {
        float4 w = *(const float4*)(sW + (kt + k4 + j) * OUT_F + cg);
        float aj0 = (j == 0) ? a0.x : (j == 1) ? a0.y : (j == 2) ? a0.z : a0.w;
        float aj1 = (j == 0) ? a1.x : (j == 1) ? a1.y : (j == 2) ? a1.z : a1.w;
        acc0.x += aj0 * w.x; acc0.y += aj0 * w.y;
        acc0.z += aj0 * w.z; acc0.w += aj0 * w.w;
        acc1.x += aj1 * w.x; acc1.y += aj1 * w.y;
        acc1.z += aj1 * w.z; acc1.w += aj1 * w.w;
      }
    }
  }

  int g0 = row0 + rg, g1 = row0 + rg + 32;
  if (g0 < N) *(float4*)(h + (size_t)g0 * OUT_F + cg) = acc0;
  if (g1 < N) *(float4*)(h + (size_t)g1 * OUT_F + cg) = acc1;
}

// out[dst[e]][o] += h[src[e]][o]; 32 lanes per edge.
__global__ __launch_bounds__(256) void aggregate_kernel(
    const int* __restrict__ src, const int* __restrict__ dst,
    const float* __restrict__ h, float* __restrict__ out, int E) {
  int lane = threadIdx.x & 31;
  int e = (blockIdx.x * 256 + threadIdx.x) >> 5;
  if (e >= E) return;
  int s = src[e];
  int d = dst[e];
  float v = h[(size_t)s * OUT_F + lane];
  unsafeAtomicAdd(out + (size_t)d * OUT_F + lane, v);
}

__global__ __launch_bounds__(256) void finalize_kernel(
    float* __restrict__ out, const float* __restrict__ deg_in,
    const float* __restrict__ bias, int N) {
  int idx = blockIdx.x * 256 + threadIdx.x;  // float4 index
  if (idx >= N * 8) return;
  int n = idx >> 3;
  int o = (idx & 7) * 4;
  float dg = deg_in[n];
  float s = dg < 1.f ? 1.f : rsqrtf(dg);
  float4 b = *(const float4*)(bias + o);
  float4 v = ((const float4*)out)[idx];
  v.x = fmaxf(fmaf(v.x, s, b.x), 0.f);
  v.y = fmaxf(fmaf(v.y, s, b.y), 0.f);
  v.z = fmaxf(fmaf(v.z, s, b.z), 0.f);
  v.w = fmaxf(fmaf(v.w, s, b.w), 0.f);
  ((float4*)out)[idx] = v;
}

extern "C" void kernel_launch(void* const* d_in, const int* in_sizes, int n_in,
                              void* d_out, int out_size, void* d_ws, size_t ws_size,
                              hipStream_t stream) {
  const float* feat = (const float*)d_in[0];
  const int* src = (const int*)d_in[1];
  const int* dst = (const int*)d_in[2];
  const float* weight = (const float*)d_in[3];
  const float* bias = (const float*)d_in[4];
  float* out = (float*)d_out;

  int N = in_sizes[0] / IN_F;
  int E = in_sizes[1];

  float* h = (float*)d_ws;                       // N*32 floats
  float* deg_out = h + (size_t)N * OUT_F;        // N floats
  float* deg_in = deg_out + N;                   // N floats

  hipMemsetAsync(deg_out, 0, (size_t)2 * N * sizeof(float), stream);
  hipMemsetAsync(out, 0, (size_t)N * OUT_F * sizeof(float), stream);

  degree_kernel<<<(E + 255) / 256, 256, 0, stream>>>(src, dst, deg_out, deg_in, E);
  gemm_kernel<<<(N + ROWS - 1) / ROWS, 256, 0, stream>>>(feat, weight, deg_out, h, N);
  aggregate_kernel<<<(E + 7) / 8, 256, 0, stream>>>(src, dst, h, out, E);
  finalize_kernel<<<(N * 8 + 255) / 256, 256, 0, stream>>>(out, deg_in, bias, N);
}

// Round 2
// 495.480 us; speedup vs baseline: 1.0467x; 1.0467x over previous
//
#include <hip/hip_runtime.h>
#include <hip/hip_bf16.h>

// GCN layer: N=100000, E=1600000, IN=256, OUT=32, fp32.
// CSR-gather pipeline (no float atomics):
//   1) degree_kernel: int counts cnt_out[src]++, cnt_in[dst]++
//   2) gemm_kernel:   h = (feat * out_deg^-0.5) @ W   [N,32]
//   3) scan1/2/3:     row_ptr = exclusive_scan(cnt_in); cursor = row_ptr
//   4) scatter_kernel: perm[cursor[dst[e]]++] = src[e]
//   5) gather_kernel: out[n] = relu(in_deg^-0.5 * sum_{e in CSR[n]} h[src[e]] + bias)
// Fallback to float-atomic scatter-add if ws_size too small for CSR arrays.

#define IN_F 256
#define OUT_F 32
#define ROWS 64
#define KT 64
#define KT_PAD (KT + 4)

__global__ __launch_bounds__(256) void degree_kernel(
    const int* __restrict__ src, const int* __restrict__ dst,
    int* __restrict__ cnt_out, int* __restrict__ cnt_in, int E) {
  int i = blockIdx.x * 256 + threadIdx.x;
  if (i < E) {
    atomicAdd(cnt_out + src[i], 1);
    atomicAdd(cnt_in + dst[i], 1);
  }
}

// h[n][o] = sum_k feat[n][k] * scale_out[n] * W[k][o]
__global__ __launch_bounds__(256, 3) void gemm_kernel(
    const float* __restrict__ feat, const float* __restrict__ W,
    const int* __restrict__ cnt_out, float* __restrict__ h, int N) {
  __shared__ float sW[IN_F * OUT_F];     // [k][o], 32 KB
  __shared__ float sF[ROWS * KT_PAD];    // [r][k] padded, ~17 KB

  int tid = threadIdx.x;
  {
    const float4* W4 = (const float4*)W;
    float4* sW4 = (float4*)sW;
#pragma unroll
    for (int i = 0; i < 8; ++i) sW4[tid + i * 256] = W4[tid + i * 256];
  }

  int row0 = blockIdx.x * ROWS;
  int rg = tid >> 3;
  int cg = (tid & 7) * 4;
  float4 acc0 = {0.f, 0.f, 0.f, 0.f};
  float4 acc1 = {0.f, 0.f, 0.f, 0.f};

  for (int kt = 0; kt < IN_F; kt += KT) {
    __syncthreads();
#pragma unroll
    for (int i = 0; i < 4; ++i) {
      int idx = tid + i * 256;
      int r = idx >> 4;
      int kk = (idx & 15) * 4;
      int gr = row0 + r;
      float4 v = {0.f, 0.f, 0.f, 0.f};
      if (gr < N) {
        float dg = (float)cnt_out[gr];
        float s = dg < 1.f ? 1.f : rsqrtf(dg);
        v = *(const float4*)(feat + (size_t)gr * IN_F + kt + kk);
        v.x *= s; v.y *= s; v.z *= s; v.w *= s;
      }
      *(float4*)(sF + r * KT_PAD + kk) = v;
    }
    __syncthreads();

    const float* fr0 = sF + rg * KT_PAD;
    const float* fr1 = sF + (rg + 32) * KT_PAD;
#pragma unroll
    for (int k4 = 0; k4 < KT; k4 += 4) {
      float4 a0 = *(const float4*)(fr0 + k4);
      float4 a1 = *(const float4*)(fr1 + k4);
#pragma unroll
      for (int j = 0; j < 4; ++j) {
        float4 w = *(const float4*)(sW + (kt + k4 + j) * OUT_F + cg);
        float aj0 = (j == 0) ? a0.x : (j == 1) ? a0.y : (j == 2) ? a0.z : a0.w;
        float aj1 = (j == 0) ? a1.x : (j == 1) ? a1.y : (j == 2) ? a1.z : a1.w;
        acc0.x += aj0 * w.x; acc0.y += aj0 * w.y;
        acc0.z += aj0 * w.z; acc0.w += aj0 * w.w;
        acc1.x += aj1 * w.x; acc1.y += aj1 * w.y;
        acc1.z += aj1 * w.z; acc1.w += aj1 * w.w;
      }
    }
  }

  int g0 = row0 + rg, g1 = row0 + rg + 32;
  if (g0 < N) *(float4*)(h + (size_t)g0 * OUT_F + cg) = acc0;
  if (g1 < N) *(float4*)(h + (size_t)g1 * OUT_F + cg) = acc1;
}

// ---- 3-phase exclusive scan of cnt_in -> row_ptr ----
__global__ __launch_bounds__(256) void scan1_kernel(
    const int* __restrict__ cnt, int* __restrict__ row_ptr,
    int* __restrict__ bsums, int N) {
  int tid = threadIdx.x;
  int i = blockIdx.x * 256 + tid;
  int v = (i < N) ? cnt[i] : 0;
  int x = v;
#pragma unroll
  for (int d = 1; d < 64; d <<= 1) {
    int y = __shfl_up(x, d, 64);
    if ((tid & 63) >= d) x += y;
  }
  __shared__ int wsum[4];
  if ((tid & 63) == 63) wsum[tid >> 6] = x;
  __syncthreads();
  int off = 0;
#pragma unroll
  for (int w = 0; w < 4; ++w) off += (w < (tid >> 6)) ? wsum[w] : 0;
  if (i < N) row_ptr[i] = off + x - v;
  if (tid == 255) bsums[blockIdx.x] = off + x;
}

__global__ __launch_bounds__(512) void scan2_kernel(int* __restrict__ bsums, int NB) {
  __shared__ int tmp[512];
  int tid = threadIdx.x;
  int v = (tid < NB) ? bsums[tid] : 0;
  tmp[tid] = v;
  __syncthreads();
  for (int d = 1; d < 512; d <<= 1) {
    int t = (tid >= d) ? tmp[tid - d] : 0;
    __syncthreads();
    tmp[tid] += t;
    __syncthreads();
  }
  if (tid < NB) bsums[tid] = tmp[tid] - v;
}

__global__ __launch_bounds__(256) void scan3_kernel(
    int* __restrict__ row_ptr, int* __restrict__ cursor,
    const int* __restrict__ bsums, int N) {
  int i = blockIdx.x * 256 + threadIdx.x;
  if (i < N) {
    int r = row_ptr[i] + bsums[i >> 8];
    row_ptr[i] = r;
    cursor[i] = r;
  }
}

__global__ __launch_bounds__(256) void scatter_kernel(
    const int* __restrict__ src, const int* __restrict__ dst,
    int* __restrict__ cursor, int* __restrict__ perm, int E) {
  int e = blockIdx.x * 256 + threadIdx.x;
  if (e < E) {
    int p = atomicAdd(cursor + dst[e], 1);
    perm[p] = src[e];
  }
}

// One 32-lane group per dst node; fused in_deg scale + bias + relu.
__global__ __launch_bounds__(256) void gather_kernel(
    const int* __restrict__ row_ptr, const int* __restrict__ cnt_in,
    const int* __restrict__ perm, const float* __restrict__ h,
    const float* __restrict__ bias, float* __restrict__ out, int N) {
  int lane = threadIdx.x & 31;
  int node = (blockIdx.x * 256 + threadIdx.x) >> 5;
  if (node >= N) return;
  int start = row_ptr[node];
  int deg = cnt_in[node];
  int end = start + deg;
  float acc = 0.f;
  for (int j = start; j < end; j += 32) {
    int sidx = (j + lane < end) ? perm[j + lane] : 0;
    int m = min(32, end - j);
    for (int t = 0; t < m; ++t) {
      int s = __shfl(sidx, t, 32);
      acc += h[(size_t)s * OUT_F + lane];
    }
  }
  float sc = deg > 0 ? rsqrtf((float)deg) : 1.f;
  float r = fmaf(acc, sc, bias[lane]);
  out[(size_t)node * OUT_F + lane] = fmaxf(r, 0.f);
}

// ---- fallback (float-atomic) path ----
__global__ __launch_bounds__(256) void aggregate_kernel(
    const int* __restrict__ src, const int* __restrict__ dst,
    const float* __restrict__ h, float* __restrict__ out, int E) {
  int lane = threadIdx.x & 31;
  int e = (blockIdx.x * 256 + threadIdx.x) >> 5;
  if (e >= E) return;
  float v = h[(size_t)src[e] * OUT_F + lane];
  unsafeAtomicAdd(out + (size_t)dst[e] * OUT_F + lane, v);
}

__global__ __launch_bounds__(256) void finalize_kernel(
    float* __restrict__ out, const int* __restrict__ cnt_in,
    const float* __restrict__ bias, int N) {
  int idx = blockIdx.x * 256 + threadIdx.x;
  if (idx >= N * 8) return;
  int n = idx >> 3;
  int o = (idx & 7) * 4;
  float dg = (float)cnt_in[n];
  float s = dg < 1.f ? 1.f : rsqrtf(dg);
  float4 b = *(const float4*)(bias + o);
  float4 v = ((const float4*)out)[idx];
  v.x = fmaxf(fmaf(v.x, s, b.x), 0.f);
  v.y = fmaxf(fmaf(v.y, s, b.y), 0.f);
  v.z = fmaxf(fmaf(v.z, s, b.z), 0.f);
  v.w = fmaxf(fmaf(v.w, s, b.w), 0.f);
  ((float4*)out)[idx] = v;
}

extern "C" void kernel_launch(void* const* d_in, const int* in_sizes, int n_in,
                              void* d_out, int out_size, void* d_ws, size_t ws_size,
                              hipStream_t stream) {
  const float* feat = (const float*)d_in[0];
  const int* src = (const int*)d_in[1];
  const int* dst = (const int*)d_in[2];
  const float* weight = (const float*)d_in[3];
  const float* bias = (const float*)d_in[4];
  float* out = (float*)d_out;

  int N = in_sizes[0] / IN_F;
  int E = in_sizes[1];

  float* h = (float*)d_ws;                 // N*32 f
  int* cnt_out = (int*)(h + (size_t)N * OUT_F);  // N
  int* cnt_in = cnt_out + N;               // N
  int* row_ptr = cnt_in + N;               // N
  int* cursor = row_ptr + N;               // N
  int* bsums = cursor + N;                 // 1024
  int* perm = bsums + 1024;                // E

  size_t need_csr = ((size_t)N * OUT_F + 4 * (size_t)N + 1024 + (size_t)E) * 4;
  bool use_csr = ws_size >= need_csr;

  hipMemsetAsync(cnt_out, 0, (size_t)2 * N * sizeof(int), stream);

  degree_kernel<<<(E + 255) / 256, 256, 0, stream>>>(src, dst, cnt_out, cnt_in, E);
  gemm_kernel<<<(N + ROWS - 1) / ROWS, 256, 0, stream>>>(feat, weight, cnt_out, h, N);

  if (use_csr) {
    int NB = (N + 255) / 256;
    scan1_kernel<<<NB, 256, 0, stream>>>(cnt_in, row_ptr, bsums, N);
    scan2_kernel<<<1, 512, 0, stream>>>(bsums, NB);
    scan3_kernel<<<NB, 256, 0, stream>>>(row_ptr, cursor, bsums, N);
    scatter_kernel<<<(E + 255) / 256, 256, 0, stream>>>(src, dst, cursor, perm, E);
    gather_kernel<<<(N * 32 + 255) / 256, 256, 0, stream>>>(
        row_ptr, cnt_in, perm, h, bias, out, N);
  } else {
    hipMemsetAsync(out, 0, (size_t)N * OUT_F * sizeof(float), stream);
    aggregate_kernel<<<(E + 7) / 8, 256, 0, stream>>>(src, dst, h, out, E);
    finalize_kernel<<<(N * 8 + 255) / 256, 256, 0, stream>>>(out, cnt_in, bias, N);
  }
}